// Round 1
// baseline (4237.722 us; speedup 1.0000x reference)
//
#include <hip/hip_runtime.h>

#define TEMP 0.0005f

// ---------------------------------------------------------------------------
// Generic conv1d (SAME padding, stride 1), implicit GEMM, fp32.
// in:  [B][Cin][T]   w: [Cout][Cin][K]   bias: [Cout]   out: [B][Cout][T]
// Block: (16,16)=256 threads. Tile: 64 co x 64 t, Cin chunked by 32.
// Each thread: 4x4 (co x t) register micro-tile.
// tx -> t (coalesced), ty -> co.
// ---------------------------------------------------------------------------
template<int K, bool RELU>
__global__ __launch_bounds__(256) void conv1d_k(
    const float* __restrict__ in, const float* __restrict__ w,
    const float* __restrict__ bias, float* __restrict__ out,
    int Cin, int Cout, int T)
{
  constexpr int P  = K / 2;
  constexpr int TW = 64 + K - 1;
  constexpr int WROW = 32 * K + 1;   // +1 pad: odd stride -> no bank conflict on co-strided reads

  __shared__ float in_s[32][TW];
  __shared__ float w_s[64][WROW];

  const int b   = blockIdx.z;
  const int t0  = blockIdx.x * 64;
  const int co0 = blockIdx.y * 64;
  const int tx = threadIdx.x, ty = threadIdx.y;
  const int tid = ty * 16 + tx;

  const float* inb = in + (size_t)b * Cin * T;

  float acc[4][4];
  #pragma unroll
  for (int j = 0; j < 4; ++j)
    #pragma unroll
    for (int i = 0; i < 4; ++i) acc[j][i] = 0.f;

  for (int ci0 = 0; ci0 < Cin; ci0 += 32) {
    // stage input tile [32][TW], zero-padded at T edges / Cin tail
    for (int idx = tid; idx < 32 * TW; idx += 256) {
      int ci = idx / TW, jj = idx - ci * TW;
      int c = ci0 + ci;
      int t = t0 + jj - P;
      float v = 0.f;
      if (c < Cin && t >= 0 && t < T) v = inb[(size_t)c * T + t];
      in_s[ci][jj] = v;
    }
    // stage weights [64][32*K] (row r = ci_local*K + kh, matches global layout)
    for (int idx = tid; idx < 64 * 32 * K; idx += 256) {
      int co = idx / (32 * K), r = idx - co * (32 * K);
      int c = ci0 + r / K;
      int cog = co0 + co;
      float v = 0.f;
      if (cog < Cout && c < Cin) v = w[((size_t)cog * Cin + c) * K + (r % K)];
      w_s[co][r] = v;
    }
    __syncthreads();

    #pragma unroll 2
    for (int ci = 0; ci < 32; ++ci) {
      #pragma unroll
      for (int kh = 0; kh < K; ++kh) {
        float wv[4], iv[4];
        #pragma unroll
        for (int j = 0; j < 4; ++j) wv[j] = w_s[ty + 16 * j][ci * K + kh];
        #pragma unroll
        for (int i = 0; i < 4; ++i) iv[i] = in_s[ci][tx + 16 * i + kh];
        #pragma unroll
        for (int j = 0; j < 4; ++j)
          #pragma unroll
          for (int i = 0; i < 4; ++i) acc[j][i] += wv[j] * iv[i];
      }
    }
    __syncthreads();
  }

  #pragma unroll
  for (int j = 0; j < 4; ++j) {
    int co = co0 + ty + 16 * j;
    if (co >= Cout) continue;
    float bv = bias[co];
    #pragma unroll
    for (int i = 0; i < 4; ++i) {
      int t = t0 + tx + 16 * i;
      if (t >= T) continue;
      float v = acc[j][i] + bv;
      if (RELU) v = fmaxf(v, 0.f);
      out[((size_t)b * Cout + co) * T + t] = v;
    }
  }
}

// ---------------------------------------------------------------------------
// Embedding gather: x[b][e][s] = emb[ph[b*512+s]][e];  (B=16, EMB=512, TK=512)
// ---------------------------------------------------------------------------
__global__ __launch_bounds__(256) void gather_k(
    const int* __restrict__ ph, const float* __restrict__ emb,
    float* __restrict__ x)
{
  int idx = blockIdx.x * 256 + threadIdx.x;     // 16*512*512 total
  int s = idx & 511;
  int e = (idx >> 9) & 511;
  int b = idx >> 18;
  int p = ph[b * 512 + s];
  x[idx] = emb[p * 512 + e];
}

// ---------------------------------------------------------------------------
// Sum of squares along channel dim: o[b][t] = sum_c x[b][c][t]^2
// ---------------------------------------------------------------------------
__global__ __launch_bounds__(256) void sumsq_k(
    const float* __restrict__ x, float* __restrict__ o, int C, int T)
{
  int idx = blockIdx.x * 256 + threadIdx.x;     // B*T total (multiple of 256)
  int b = idx / T, t = idx - b * T;
  const float* p = x + (size_t)b * C * T + t;
  float s = 0.f;
  for (int c = 0; c < C; ++c) { float v = p[(size_t)c * T]; s += v * v; }
  o[idx] = s;
}

// ---------------------------------------------------------------------------
// attention[b][t][s] = -TEMP * (q2[b][t] + k2[b][s] - 2 * sum_c q[b][c][t]*k[b][c][s])
// Tile 64 t x 64 s, K=80 fully staged in LDS. tx -> s (coalesced out), ty -> t.
// ---------------------------------------------------------------------------
__global__ __launch_bounds__(256) void attn_k(
    const float* __restrict__ q, const float* __restrict__ k,
    const float* __restrict__ q2, const float* __restrict__ k2,
    float* __restrict__ out)
{
  __shared__ float q_s[80][65];
  __shared__ float k_s[80][65];
  const int b  = blockIdx.z;
  const int t0 = blockIdx.y * 64;
  const int s0 = blockIdx.x * 64;
  const int tx = threadIdx.x, ty = threadIdx.y;
  const int tid = ty * 16 + tx;

  for (int idx = tid; idx < 80 * 64; idx += 256) {
    int c = idx >> 6, j = idx & 63;
    int t = t0 + j;
    q_s[c][j] = (t < 4000) ? q[((size_t)b * 80 + c) * 4000 + t] : 0.f;
    k_s[c][j] = k[((size_t)b * 80 + c) * 512 + s0 + j];
  }
  __syncthreads();

  float acc[4][4];
  #pragma unroll
  for (int j = 0; j < 4; ++j)
    #pragma unroll
    for (int i = 0; i < 4; ++i) acc[j][i] = 0.f;

  #pragma unroll 4
  for (int c = 0; c < 80; ++c) {
    float qv[4], kv[4];
    #pragma unroll
    for (int j = 0; j < 4; ++j) qv[j] = q_s[c][ty + 16 * j];
    #pragma unroll
    for (int i = 0; i < 4; ++i) kv[i] = k_s[c][tx + 16 * i];
    #pragma unroll
    for (int j = 0; j < 4; ++j)
      #pragma unroll
      for (int i = 0; i < 4; ++i) acc[j][i] += qv[j] * kv[i];
  }

  #pragma unroll
  for (int j = 0; j < 4; ++j) {
    int t = t0 + ty + 16 * j;
    if (t >= 4000) continue;
    float q2v = q2[b * 4000 + t];
    #pragma unroll
    for (int i = 0; i < 4; ++i) {
      int s = s0 + tx + 16 * i;
      float v = -TEMP * (q2v + k2[b * 512 + s] - 2.f * acc[j][i]);
      out[((size_t)b * 4000 + t) * 512 + s] = v;
    }
  }
}

// ---------------------------------------------------------------------------
extern "C" void kernel_launch(void* const* d_in, const int* in_sizes, int n_in,
                              void* d_out, int out_size, void* d_ws, size_t ws_size,
                              hipStream_t stream)
{
  const float* mels = (const float*)d_in[0];
  const int*   ph   = (const int*)  d_in[1];
  const float* emb  = (const float*)d_in[2];
  const float* tw1  = (const float*)d_in[3];
  const float* tb1  = (const float*)d_in[4];
  const float* tw2  = (const float*)d_in[5];
  const float* tb2  = (const float*)d_in[6];
  const float* tw3  = (const float*)d_in[7];
  const float* tb3  = (const float*)d_in[8];
  const float* ow1  = (const float*)d_in[9];
  const float* ob1  = (const float*)d_in[10];
  const float* ow2  = (const float*)d_in[11];
  const float* ob2  = (const float*)d_in[12];
  const float* mw1  = (const float*)d_in[13];
  const float* mb1  = (const float*)d_in[14];
  const float* mw2  = (const float*)d_in[15];
  const float* mb2  = (const float*)d_in[16];
  const float* mw3  = (const float*)d_in[17];
  const float* mb3  = (const float*)d_in[18];
  float* out = (float*)d_out;
  float* ws  = (float*)d_ws;

  // Workspace layout (floats). A/B are freed after the q-path; x0/x1/y reuse them.
  float* A  = ws;                       // 16*256*4000 = 16,384,000
  float* Bb = ws + 16384000;            // 16*128*4000 =  8,192,000
  float* q  = ws + 24576000;            // 16*80*4000  =  5,120,000
  float* kb = ws + 29696000;            // 16*80*512   =    655,360
  float* q2 = ws + 30351360;            // 16*4000     =     64,000
  float* k2 = ws + 30415360;            // 16*512      =      8,192
  float* x0 = ws;                       // 16*512*512  =  4,194,304 (reuses A)
  float* x1 = ws + 4194304;             //   "         (reuses A)
  float* y  = ws + 8388608;             // 16*1024*512 =  8,388,608 (reuses A+B)

  dim3 blk(16, 16);

  // q path (T=4000)
  conv1d_k<3, true ><<<dim3(63,  4, 16), blk, 0, stream>>>(mels, mw1, mb1, A,   80, 256, 4000);
  conv1d_k<3, true ><<<dim3(63,  2, 16), blk, 0, stream>>>(A,    mw2, mb2, Bb, 256, 128, 4000);
  conv1d_k<1, false><<<dim3(63,  2, 16), blk, 0, stream>>>(Bb,   mw3, mb3, q,  128,  80, 4000);

  // k path (T=512)
  gather_k<<<16384, 256, 0, stream>>>(ph, emb, x0);
  conv1d_k<5, true ><<<dim3( 8,  8, 16), blk, 0, stream>>>(x0, tw1, tb1, x1, 512,  512, 512);
  conv1d_k<5, true ><<<dim3( 8,  8, 16), blk, 0, stream>>>(x1, tw2, tb2, x0, 512,  512, 512);
  conv1d_k<5, true ><<<dim3( 8,  8, 16), blk, 0, stream>>>(x0, tw3, tb3, x1, 512,  512, 512);
  conv1d_k<3, true ><<<dim3( 8, 16, 16), blk, 0, stream>>>(x1, ow1, ob1, y,  512, 1024, 512);
  conv1d_k<1, false><<<dim3( 8,  2, 16), blk, 0, stream>>>(y,  ow2, ob2, kb, 1024, 80, 512);

  // reductions + fused distance epilogue
  sumsq_k<<<250, 256, 0, stream>>>(q,  q2, 80, 4000);
  sumsq_k<<< 32, 256, 0, stream>>>(kb, k2, 80, 512);
  attn_k<<<dim3(8, 63, 16), blk, 0, stream>>>(q, kb, q2, k2, out);
}

// Round 2
// 562.000 us; speedup vs baseline: 7.5404x; 7.5404x over previous
//
#include <hip/hip_runtime.h>

#define TEMP 0.0005f

typedef __attribute__((ext_vector_type(8))) short short8v;
typedef __attribute__((ext_vector_type(4))) float float4v;

static __device__ __forceinline__ unsigned short f2b(float f) {
  union { float f; unsigned int u; } x; x.f = f;
  unsigned int r = x.u + 0x7fffu + ((x.u >> 16) & 1u);
  return (unsigned short)(r >> 16);
}
static __device__ __forceinline__ float b2f(unsigned short h) {
  union { unsigned int u; float f; } x; x.u = ((unsigned int)h) << 16;
  return x.f;
}

// ---------------------------------------------------------------------------
// Weight convert+transpose: w[Cout][Cin][K] f32 -> wT[Cout][K*Cin] bf16
// ---------------------------------------------------------------------------
__global__ __launch_bounds__(256) void wcvt_k(
    const float* __restrict__ w, unsigned short* __restrict__ wT,
    int Cout, int Cin, int K)
{
  int o = blockIdx.x * 256 + threadIdx.x;
  if (o >= Cout * Cin * K) return;
  int co = o / (K * Cin);
  int r  = o - co * (K * Cin);
  int kh = r / Cin;
  int ci = r - kh * Cin;
  wT[o] = f2b(w[(co * Cin + ci) * K + kh]);
}

// ---------------------------------------------------------------------------
// mels [16][80][4000] f32 -> melsT [16][4000][80] bf16 (LDS transpose)
// ---------------------------------------------------------------------------
__global__ __launch_bounds__(256) void melscvt_k(
    const float* __restrict__ in, unsigned short* __restrict__ out)
{
  __shared__ float s[80][65];
  const int b  = blockIdx.y;
  const int t0 = blockIdx.x * 64;
  const int tid = threadIdx.x;
  for (int idx = tid; idx < 80 * 64; idx += 256) {
    int c = idx >> 6, tl = idx & 63;
    int t = t0 + tl;
    s[c][tl] = (t < 4000) ? in[((size_t)b * 80 + c) * 4000 + t] : 0.f;
  }
  __syncthreads();
  for (int idx = tid; idx < 64 * 80; idx += 256) {
    int tl = idx / 80, c = idx - tl * 80;
    int t = t0 + tl;
    if (t < 4000) out[((size_t)b * 4000 + t) * 80 + c] = f2b(s[c][tl]);
  }
}

// ---------------------------------------------------------------------------
// Embedding gather: x[bs][e] = bf16(emb[ph[bs]][e]), one block per (b,s)
// ---------------------------------------------------------------------------
__global__ __launch_bounds__(256) void gather_k(
    const int* __restrict__ ph, const float* __restrict__ emb,
    unsigned short* __restrict__ x)
{
  const int bs = blockIdx.x;
  const int p = ph[bs];
  const float* e = emb + (size_t)p * 512;
  unsigned short* o = x + (size_t)bs * 512;
  int i = threadIdx.x * 2;
  float2 v = *(const float2*)&e[i];
  unsigned int pk = (unsigned)f2b(v.x) | ((unsigned)f2b(v.y) << 16);
  *(unsigned int*)&o[i] = pk;
}

// ---------------------------------------------------------------------------
// MFMA conv1d (SAME, stride 1), bf16 in/out, fp32 accum.
// in:  [B][T][Cin] bf16.  wT: [Cout][K*Cin] bf16.  out: [B][T][Cout] bf16.
// Block tile: 64 co x 128 t, 4 waves each 32co x 64t, 16x16x32 frags.
// LDS rows padded so row strides are ~20 banks mod 32 (2-way = free).
// ---------------------------------------------------------------------------
template<int K, bool RELU>
__global__ __launch_bounds__(256) void conv_mfma(
    const unsigned short* __restrict__ in,
    const unsigned short* __restrict__ wT,
    const float* __restrict__ bias,
    unsigned short* __restrict__ out,
    int Cin, int Cout, int T)
{
  constexpr int P  = K / 2;
  constexpr int BT = 128;
  constexpr int BC = 64;
  constexpr int TW = BT + K - 1;
  constexpr int WR = K * 32 + 8;

  __shared__ unsigned short in_s[TW][40];   // [tloc][ci] bf16, row 80B
  __shared__ unsigned short w_s[BC][WR];    // [co][kh*32+ci]

  const int b    = blockIdx.z;
  const int t0   = blockIdx.x * BT;
  const int co0  = blockIdx.y * BC;
  const int tid  = threadIdx.x;
  const int lane = tid & 63;
  const int wv   = tid >> 6;
  const int wco  = (wv & 1) << 5;   // 0,32
  const int wt   = (wv >> 1) << 6;  // 0,64
  const int l15  = lane & 15;
  const int lq   = lane >> 4;       // 0..3

  const unsigned short* inb = in + (size_t)b * T * Cin;
  const size_t wrow = (size_t)K * Cin;

  float4v acc[2][4];
  #pragma unroll
  for (int m = 0; m < 2; ++m)
    #pragma unroll
    for (int n = 0; n < 4; ++n) { float4v z = {0.f,0.f,0.f,0.f}; acc[m][n] = z; }

  for (int ci0 = 0; ci0 < Cin; ci0 += 32) {
    // stage input tile: TW rows x 32 ci, 16B granules, zero-padded
    for (int g = tid; g < TW * 4; g += 256) {
      int tl = g >> 2, q = g & 3;
      int gt = t0 + tl - P;
      int ci = ci0 + q * 8;
      short8v v = {};
      if (gt >= 0 && gt < T && ci < Cin)
        v = *(const short8v*)&inb[(size_t)gt * Cin + ci];
      *(short8v*)&in_s[tl][q * 8] = v;
    }
    // stage weights: BC rows x K*32
    for (int g = tid; g < BC * K * 4; g += 256) {
      int co = g / (K * 4);
      int r  = g - co * (K * 4);
      int kh = r >> 2, q = r & 3;
      int ci = ci0 + q * 8;
      short8v v = {};
      if (co0 + co < Cout && ci < Cin)
        v = *(const short8v*)&wT[(size_t)(co0 + co) * wrow + (size_t)kh * Cin + ci];
      *(short8v*)&w_s[co][kh * 32 + q * 8] = v;
    }
    __syncthreads();

    #pragma unroll
    for (int kh = 0; kh < K; ++kh) {
      short8v a0 = *(const short8v*)&w_s[wco + l15     ][kh * 32 + lq * 8];
      short8v a1 = *(const short8v*)&w_s[wco + 16 + l15][kh * 32 + lq * 8];
      short8v b0 = *(const short8v*)&in_s[wt      + l15 + kh][lq * 8];
      short8v b1 = *(const short8v*)&in_s[wt + 16 + l15 + kh][lq * 8];
      short8v b2 = *(const short8v*)&in_s[wt + 32 + l15 + kh][lq * 8];
      short8v b3 = *(const short8v*)&in_s[wt + 48 + l15 + kh][lq * 8];
      acc[0][0] = __builtin_amdgcn_mfma_f32_16x16x32_bf16(a0, b0, acc[0][0], 0, 0, 0);
      acc[0][1] = __builtin_amdgcn_mfma_f32_16x16x32_bf16(a0, b1, acc[0][1], 0, 0, 0);
      acc[0][2] = __builtin_amdgcn_mfma_f32_16x16x32_bf16(a0, b2, acc[0][2], 0, 0, 0);
      acc[0][3] = __builtin_amdgcn_mfma_f32_16x16x32_bf16(a0, b3, acc[0][3], 0, 0, 0);
      acc[1][0] = __builtin_amdgcn_mfma_f32_16x16x32_bf16(a1, b0, acc[1][0], 0, 0, 0);
      acc[1][1] = __builtin_amdgcn_mfma_f32_16x16x32_bf16(a1, b1, acc[1][1], 0, 0, 0);
      acc[1][2] = __builtin_amdgcn_mfma_f32_16x16x32_bf16(a1, b2, acc[1][2], 0, 0, 0);
      acc[1][3] = __builtin_amdgcn_mfma_f32_16x16x32_bf16(a1, b3, acc[1][3], 0, 0, 0);
    }
    __syncthreads();
  }

  // epilogue: D col = lane&15 -> t, row = (lane>>4)*4 + r -> co
  #pragma unroll
  for (int m = 0; m < 2; ++m) {
    int co = co0 + wco + m * 16 + (lq << 2);
    if (co >= Cout) continue;
    float4v bv = *(const float4v*)&bias[co];
    #pragma unroll
    for (int n = 0; n < 4; ++n) {
      int t = t0 + wt + n * 16 + l15;
      if (t >= T) continue;
      float v0 = acc[m][n][0] + bv[0];
      float v1 = acc[m][n][1] + bv[1];
      float v2 = acc[m][n][2] + bv[2];
      float v3 = acc[m][n][3] + bv[3];
      if (RELU) {
        v0 = fmaxf(v0, 0.f); v1 = fmaxf(v1, 0.f);
        v2 = fmaxf(v2, 0.f); v3 = fmaxf(v3, 0.f);
      }
      unsigned long long pk =
          (unsigned long long)((unsigned)f2b(v0) | ((unsigned)f2b(v1) << 16)) |
          ((unsigned long long)((unsigned)f2b(v2) | ((unsigned)f2b(v3) << 16)) << 32);
      *(unsigned long long*)&out[((size_t)b * T + t) * Cout + co] = pk;
    }
  }
}

// ---------------------------------------------------------------------------
// Row sum of squares: o[row] = sum_c x[row][c]^2, rows of 80 bf16
// ---------------------------------------------------------------------------
__global__ __launch_bounds__(256) void sumsq_k(
    const unsigned short* __restrict__ x, float* __restrict__ o, int N)
{
  int idx = blockIdx.x * 256 + threadIdx.x;
  if (idx >= N) return;
  const unsigned short* r = x + (size_t)idx * 80;
  float s = 0.f;
  #pragma unroll
  for (int g = 0; g < 10; ++g) {
    short8v v = *(const short8v*)&r[g * 8];
    #pragma unroll
    for (int j = 0; j < 8; ++j) { float f = b2f((unsigned short)v[j]); s += f * f; }
  }
  o[idx] = s;
}

// ---------------------------------------------------------------------------
// attention[b][t][s] = -TEMP*(q2[t]+k2[s]-2*qk), qk via MFMA over C=80 (pad 96)
// q: [16][4000][80] bf16, k: [16][512][80] bf16, out fp32 [16][4000][512]
// ---------------------------------------------------------------------------
__global__ __launch_bounds__(256) void attn_mfma(
    const unsigned short* __restrict__ q, const unsigned short* __restrict__ k,
    const float* __restrict__ q2, const float* __restrict__ k2,
    float* __restrict__ out)
{
  __shared__ unsigned short q_s[64][104];
  __shared__ unsigned short k_s[64][104];
  const int b  = blockIdx.z;
  const int t0 = blockIdx.y * 64;
  const int s0 = blockIdx.x * 64;
  const int tid  = threadIdx.x;
  const int lane = tid & 63;
  const int wv   = tid >> 6;
  const int wt   = (wv & 1) << 5;   // 0,32
  const int ws   = (wv >> 1) << 5;  // 0,32
  const int l15  = lane & 15;
  const int lq   = lane >> 4;

  for (int g = tid; g < 64 * 12; g += 256) {
    int row = g / 12, c = (g - row * 12) * 8;
    short8v vq = {}, vk = {};
    int t = t0 + row;
    if (c < 80) {
      if (t < 4000) vq = *(const short8v*)&q[((size_t)b * 4000 + t) * 80 + c];
      vk = *(const short8v*)&k[((size_t)b * 512 + s0 + row) * 80 + c];
    }
    *(short8v*)&q_s[row][c] = vq;
    *(short8v*)&k_s[row][c] = vk;
  }
  __syncthreads();

  float4v acc[2][2];
  #pragma unroll
  for (int m = 0; m < 2; ++m)
    #pragma unroll
    for (int n = 0; n < 2; ++n) { float4v z = {0.f,0.f,0.f,0.f}; acc[m][n] = z; }

  #pragma unroll
  for (int ks = 0; ks < 3; ++ks) {
    short8v a0 = *(const short8v*)&q_s[wt      + l15][ks * 32 + lq * 8];
    short8v a1 = *(const short8v*)&q_s[wt + 16 + l15][ks * 32 + lq * 8];
    short8v b0 = *(const short8v*)&k_s[ws      + l15][ks * 32 + lq * 8];
    short8v b1 = *(const short8v*)&k_s[ws + 16 + l15][ks * 32 + lq * 8];
    acc[0][0] = __builtin_amdgcn_mfma_f32_16x16x32_bf16(a0, b0, acc[0][0], 0, 0, 0);
    acc[0][1] = __builtin_amdgcn_mfma_f32_16x16x32_bf16(a0, b1, acc[0][1], 0, 0, 0);
    acc[1][0] = __builtin_amdgcn_mfma_f32_16x16x32_bf16(a1, b0, acc[1][0], 0, 0, 0);
    acc[1][1] = __builtin_amdgcn_mfma_f32_16x16x32_bf16(a1, b1, acc[1][1], 0, 0, 0);
  }

  #pragma unroll
  for (int m = 0; m < 2; ++m) {
    #pragma unroll
    for (int r = 0; r < 4; ++r) {
      int t = t0 + wt + m * 16 + lq * 4 + r;
      if (t >= 4000) continue;
      float q2v = q2[b * 4000 + t];
      #pragma unroll
      for (int n = 0; n < 2; ++n) {
        int s = s0 + ws + n * 16 + l15;
        float v = -TEMP * (q2v + k2[b * 512 + s] - 2.f * acc[m][n][r]);
        out[((size_t)b * 4000 + t) * 512 + s] = v;
      }
    }
  }
}

// ---------------------------------------------------------------------------
extern "C" void kernel_launch(void* const* d_in, const int* in_sizes, int n_in,
                              void* d_out, int out_size, void* d_ws, size_t ws_size,
                              hipStream_t stream)
{
  const float* mels = (const float*)d_in[0];
  const int*   ph   = (const int*)  d_in[1];
  const float* emb  = (const float*)d_in[2];
  const float* tw1  = (const float*)d_in[3];
  const float* tb1  = (const float*)d_in[4];
  const float* tw2  = (const float*)d_in[5];
  const float* tb2  = (const float*)d_in[6];
  const float* tw3  = (const float*)d_in[7];
  const float* tb3  = (const float*)d_in[8];
  const float* ow1  = (const float*)d_in[9];
  const float* ob1  = (const float*)d_in[10];
  const float* ow2  = (const float*)d_in[11];
  const float* ob2  = (const float*)d_in[12];
  const float* mw1  = (const float*)d_in[13];
  const float* mb1  = (const float*)d_in[14];
  const float* mw2  = (const float*)d_in[15];
  const float* mb2  = (const float*)d_in[16];
  const float* mw3  = (const float*)d_in[17];
  const float* mb3  = (const float*)d_in[18];
  float* out = (float*)d_out;

  // ---- workspace carve (all chunks multiple of 256 B) ----
  char* base = (char*)d_ws;
  unsigned short* wTtw1 = (unsigned short*)base; base += 512 * 2560 * 2;     // 2,621,440
  unsigned short* wTtw2 = (unsigned short*)base; base += 512 * 2560 * 2;
  unsigned short* wTtw3 = (unsigned short*)base; base += 512 * 2560 * 2;
  unsigned short* wTow1 = (unsigned short*)base; base += 1024 * 1536 * 2;    // 3,145,728
  unsigned short* wTmw1 = (unsigned short*)base; base += 256 * 240 * 2;      // 122,880
  unsigned short* wTmw2 = (unsigned short*)base; base += 128 * 768 * 2;      // 196,608
  unsigned short* wTmw3 = (unsigned short*)base; base += 80 * 128 * 2;       // 20,480
  unsigned short* wTow2 = (unsigned short*)base; base += 80 * 1024 * 2;      // 163,840
  unsigned short* melsT = (unsigned short*)base; base += 16 * 4000 * 80 * 2; // 10,240,000
  unsigned short* actA  = (unsigned short*)base; base += 16 * 4000 * 256 * 2;// 32,768,000
  unsigned short* actB  = (unsigned short*)base; base += 16 * 4000 * 128 * 2;// 16,384,000
  unsigned short* qb    = (unsigned short*)base; base += 16 * 4000 * 80 * 2; // 10,240,000
  unsigned short* x0    = (unsigned short*)base; base += 16 * 512 * 512 * 2; // 8,388,608
  unsigned short* x1    = (unsigned short*)base; base += 16 * 512 * 512 * 2;
  unsigned short* yb    = (unsigned short*)base; base += 16 * 512 * 1024 * 2;// 16,777,216
  unsigned short* kb    = (unsigned short*)base; base += 16 * 512 * 80 * 2;  // 1,310,720
  float* q2v = (float*)base; base += 64000 * 4;                              // 256,000
  float* k2v = (float*)base; base += 8192 * 4;                               // 32,768

  // ---- weight convert/transpose (bf16) ----
  wcvt_k<<<5120, 256, 0, stream>>>(tw1, wTtw1, 512, 512, 5);
  wcvt_k<<<5120, 256, 0, stream>>>(tw2, wTtw2, 512, 512, 5);
  wcvt_k<<<5120, 256, 0, stream>>>(tw3, wTtw3, 512, 512, 5);
  wcvt_k<<<6144, 256, 0, stream>>>(ow1, wTow1, 1024, 512, 3);
  wcvt_k<<<240, 256, 0, stream>>>(mw1, wTmw1, 256, 80, 3);
  wcvt_k<<<384, 256, 0, stream>>>(mw2, wTmw2, 128, 256, 3);
  wcvt_k<<<40, 256, 0, stream>>>(mw3, wTmw3, 80, 128, 1);
  wcvt_k<<<320, 256, 0, stream>>>(ow2, wTow2, 80, 1024, 1);

  // ---- input conversions ----
  melscvt_k<<<dim3(63, 16), 256, 0, stream>>>(mels, melsT);
  gather_k<<<8192, 256, 0, stream>>>(ph, emb, x0);

  // ---- q path (T=4000) ----
  conv_mfma<3, true ><<<dim3(32, 4, 16), 256, 0, stream>>>(melsT, wTmw1, mb1, actA,  80, 256, 4000);
  conv_mfma<3, true ><<<dim3(32, 2, 16), 256, 0, stream>>>(actA,  wTmw2, mb2, actB, 256, 128, 4000);
  conv_mfma<1, false><<<dim3(32, 2, 16), 256, 0, stream>>>(actB,  wTmw3, mb3, qb,   128,  80, 4000);

  // ---- k path (T=512) ----
  conv_mfma<5, true ><<<dim3(4,  8, 16), 256, 0, stream>>>(x0, wTtw1, tb1, x1,  512,  512, 512);
  conv_mfma<5, true ><<<dim3(4,  8, 16), 256, 0, stream>>>(x1, wTtw2, tb2, x0,  512,  512, 512);
  conv_mfma<5, true ><<<dim3(4,  8, 16), 256, 0, stream>>>(x0, wTtw3, tb3, x1,  512,  512, 512);
  conv_mfma<3, true ><<<dim3(4, 16, 16), 256, 0, stream>>>(x1, wTow1, ob1, yb,  512, 1024, 512);
  conv_mfma<1, false><<<dim3(4,  2, 16), 256, 0, stream>>>(yb, wTow2, ob2, kb, 1024,   80, 512);

  // ---- reductions + fused distance epilogue ----
  sumsq_k<<<250, 256, 0, stream>>>(qb, q2v, 64000);
  sumsq_k<<<32, 256, 0, stream>>>(kb, k2v, 8192);
  attn_mfma<<<dim3(8, 63, 16), 256, 0, stream>>>(qb, kb, q2v, k2v, out);
}